// Round 7
// baseline (269.774 us; speedup 1.0000x reference)
//
#include <hip/hip_runtime.h>
#include <hip/hip_bf16.h>
#include <stdint.h>

#define D_MODEL 1024
#define D_INNER 2048
#define NEXP 8
#define TOPK 2
#define T256 40   // max 256-row tiles: 8192/256 + 7 = 39, padded
#define T128 72   // max 128-row tiles: 8192/128 + 7 = 71, padded

typedef float f32x4 __attribute__((ext_vector_type(4)));
typedef short bf16x8 __attribute__((ext_vector_type(8)));

#define MEMFENCE asm volatile("" ::: "memory")

__device__ __forceinline__ unsigned short f2b(float f) {
    union { float f; uint32_t u; } v; v.f = f;
    uint32_t u = v.u;
    return (unsigned short)((u + 0x7fffu + ((u >> 16) & 1u)) >> 16);
}

__device__ __forceinline__ void gl_lds16(const void* g, void* l) {
    __builtin_amdgcn_global_load_lds((const __attribute__((address_space(1))) void*)g,
                                     (__attribute__((address_space(3))) void*)l, 16, 0, 0);
}

// ------- cast+transpose all 3 weights: [E][K][N] fp32 -> [E][N][K] bf16 -------
__global__ __launch_bounds__(256) void tcast3_kernel(
    const float* __restrict__ gw, const float* __restrict__ uw, const float* __restrict__ dw,
    unsigned short* __restrict__ gT, unsigned short* __restrict__ uT, unsigned short* __restrict__ dT)
{
    __shared__ unsigned short S[64][68];
    int which = blockIdx.z >> 3;
    int e = blockIdx.z & 7;
    const float* in; unsigned short* out; int K, N;
    if (which == 0)      { in = gw; out = gT; K = D_MODEL; N = D_INNER; }
    else if (which == 1) { in = uw; out = uT; K = D_MODEL; N = D_INNER; }
    else                 { in = dw; out = dT; K = D_INNER; N = D_MODEL; }
    int n0 = blockIdx.x * 64, k0 = blockIdx.y * 64;
    if (n0 >= N || k0 >= K) return;
    const float* ib = in + (size_t)e * K * N;
    unsigned short* ob = out + (size_t)e * N * K;
    int tid = threadIdx.x;
    int kk = tid >> 4, nn4 = (tid & 15) * 4;
#pragma unroll
    for (int j = 0; j < 4; j++) {
        int k = kk + 16 * j;
        float4 v = *(const float4*)&ib[(size_t)(k0 + k) * N + n0 + nn4];
        ushort4 s; s.x = f2b(v.x); s.y = f2b(v.y); s.z = f2b(v.z); s.w = f2b(v.w);
        *(ushort4*)&S[k][nn4] = s;
    }
    __syncthreads();
    int nn = tid >> 4, kk4 = (tid & 15) * 4;
#pragma unroll
    for (int j = 0; j < 4; j++) {
        int n = nn + 16 * j;
        ushort4 s;
        s.x = S[kk4 + 0][n]; s.y = S[kk4 + 1][n];
        s.z = S[kk4 + 2][n]; s.w = S[kk4 + 3][n];
        *(ushort4*)&ob[(size_t)(n0 + n) * K + k0 + kk4] = s;
    }
}

// ---------------- router (+ fused x->bf16 cast): 1 wave per token ----------------
__global__ __launch_bounds__(64) void router_kernel(
    const float* __restrict__ x, const float* __restrict__ rw,
    const float* __restrict__ rb, unsigned short* __restrict__ xb,
    int* __restrict__ top_i, float* __restrict__ top_w, int T)
{
    int t = blockIdx.x;
    if (t >= T) return;
    int l = threadIdx.x;
    float xv[16];
#pragma unroll
    for (int i = 0; i < 16; i++) xv[i] = x[(size_t)t * D_MODEL + l + 64 * i];
#pragma unroll
    for (int i = 0; i < 16; i++) xb[(size_t)t * D_MODEL + l + 64 * i] = f2b(xv[i]);
    float logit[NEXP];
#pragma unroll
    for (int e = 0; e < NEXP; e++) {
        float acc = 0.f;
#pragma unroll
        for (int i = 0; i < 16; i++) acc += xv[i] * rw[e * D_MODEL + l + 64 * i];
#pragma unroll
        for (int s = 32; s > 0; s >>= 1) acc += __shfl_xor(acc, s, 64);
        logit[e] = acc + rb[e];
    }
    if (l == 0) {
        int i0 = 0; float m0 = logit[0];
#pragma unroll
        for (int e = 1; e < NEXP; e++) if (logit[e] > m0) { m0 = logit[e]; i0 = e; }
        int i1 = -1; float m1 = -3.0e38f;
#pragma unroll
        for (int e = 0; e < NEXP; e++) {
            if (e == i0) continue;
            if (logit[e] > m1) { m1 = logit[e]; i1 = e; }
        }
        float w0 = 1.f / (1.f + expf(m1 - m0));
        top_i[t * 2 + 0] = i0; top_i[t * 2 + 1] = i1;
        top_w[t * 2 + 0] = w0; top_w[t * 2 + 1] = 1.f - w0;
    }
}

// ---------------- bucket build + two compact tile worklists ----------------
// meta: [0..8] expert offsets; [16..16+T256) 256-row tiles; [64..64+T128) 128-row tiles
__global__ __launch_bounds__(256) void bucket_kernel(
    const int* __restrict__ top_i, const float* __restrict__ top_w,
    int* __restrict__ meta, int* __restrict__ tok_of_slot,
    float* __restrict__ w_of_slot, int T)
{
    __shared__ int cnt[256][NEXP];
    __shared__ int pre[256][NEXP];
    __shared__ int tot[NEXP];
    __shared__ int off[NEXP + 1];
    int tid = threadIdx.x;
    int per = (T + 255) / 256;
    int t0 = tid * per;
    for (int e = 0; e < NEXP; e++) cnt[tid][e] = 0;
    for (int t = t0; t < t0 + per && t < T; t++)
        for (int k = 0; k < TOPK; k++) cnt[tid][top_i[t * 2 + k]]++;
    __syncthreads();
    if (tid < NEXP) {
        int run = 0;
        for (int i = 0; i < 256; i++) { pre[i][tid] = run; run += cnt[i][tid]; }
        tot[tid] = run;
    }
    __syncthreads();
    if (tid == 0) {
        off[0] = 0;
        for (int e = 0; e < NEXP; e++) off[e + 1] = off[e] + tot[e];
        for (int e = 0; e <= NEXP; e++) meta[e] = off[e];
        int nt = 0;
        for (int e = 0; e < NEXP; e++)
            for (int r = off[e]; r < off[e + 1]; r += 256)
                meta[16 + nt++] = (e << 16) | r;
        for (; nt < T256; nt++) meta[16 + nt] = -1;
        nt = 0;
        for (int e = 0; e < NEXP; e++)
            for (int r = off[e]; r < off[e + 1]; r += 128)
                meta[64 + nt++] = (e << 16) | r;
        for (; nt < T128; nt++) meta[64 + nt] = -1;
    }
    __syncthreads();
    int lc[NEXP];
#pragma unroll
    for (int e = 0; e < NEXP; e++) lc[e] = 0;
    for (int t = t0; t < t0 + per && t < T; t++) {
        for (int k = 0; k < TOPK; k++) {
            int e = top_i[t * 2 + k];
            int slot = off[e] + pre[tid][e] + lc[e]++;
            tok_of_slot[slot] = t;
            w_of_slot[slot] = top_w[t * 2 + k];
        }
    }
}

// ---------------- gate+up GEMM + swiglu -> H ----------------
// 512 threads / 8 waves (4M x 2N), tile M=256 x F=128 (g AND u), BK=64,
// 2 x 64KB LDS buffers, 1 block/CU. Per K-step: stage(t+1) issued first
// (latency hides under ~2000cyc MFMA), one vmcnt(0)+barrier at step end.
__global__ __launch_bounds__(512, 2) void moe_gate_up(
    const unsigned short* __restrict__ xb, const unsigned short* __restrict__ wgT,
    const unsigned short* __restrict__ wuT, const int* __restrict__ meta,
    const int* __restrict__ tok_of_slot, unsigned short* __restrict__ H)
{
    extern __shared__ __align__(16) unsigned short lds[];   // 2 * 32768 ushorts

    int lin = blockIdx.x;
    int strip = (lin & 7) * 2 + ((lin >> 3) & 1);   // lin%8 = XCD
    int tix = lin >> 4;
    int packed = meta[16 + tix];
    if (packed < 0) return;
    int e = packed >> 16, row0 = packed & 0xffff;
    int Mloc = min(256, meta[e + 1] - row0);
    int f0 = strip * 128;

    int tid = threadIdx.x, wv = tid >> 6, lane = tid & 63;
    int c = tid & 7, rr = tid >> 3;   // staging: 64 rows x 8 chunks per round

    const unsigned short* srcA[4];
    const unsigned short* srcG[2];
    const unsigned short* srcU[2];
#pragma unroll
    for (int j = 0; j < 4; j++) {
        int row = j * 64 + rr;
        int slot = row0 + ((row < Mloc) ? row : 0);
        srcA[j] = xb + (size_t)tok_of_slot[slot] * D_MODEL + 8 * (c ^ (row & 7));
    }
#pragma unroll
    for (int j = 0; j < 2; j++) {
        int row = j * 64 + rr;
        size_t wb = (size_t)e * D_MODEL * D_INNER + (size_t)(f0 + row) * D_MODEL + 8 * (c ^ (row & 7));
        srcG[j] = wgT + wb; srcU[j] = wuT + wb;
    }

    int wm = wv >> 1, wn = wv & 1;
    int lrow = lane & 15, kgrp = lane >> 4;
    int sw = lrow & 7;
    int co0 = 8 * (kgrp ^ sw);          // ks=0 chunk (swizzled)
    int co1 = 8 * ((4 + kgrp) ^ sw);    // ks=1 chunk

    int arow[4], brow[4];
#pragma unroll
    for (int i = 0; i < 4; i++) arow[i] = (wm * 64 + i * 16 + lrow) * 64;
#pragma unroll
    for (int i = 0; i < 4; i++) brow[i] = (wn * 64 + i * 16 + lrow) * 64;

    f32x4 accg[4][4], accu[4][4];
#pragma unroll
    for (int i = 0; i < 4; i++)
#pragma unroll
        for (int j = 0; j < 4; j++) {
            accg[i][j] = (f32x4){0.f, 0.f, 0.f, 0.f};
            accu[i][j] = (f32x4){0.f, 0.f, 0.f, 0.f};
        }

    auto stage = [&](int u) {   // 8 gl_lds16 per thread: A 32KB + Bg 16KB + Bu 16KB
        int kk = u * 64;
        unsigned short* base = lds + (u & 1) * 32768;
#pragma unroll
        for (int j = 0; j < 4; j++)
            gl_lds16(srcA[j] + kk, base + (j * 512 + wv * 64) * 8);
#pragma unroll
        for (int j = 0; j < 2; j++) {
            gl_lds16(srcG[j] + kk, base + 16384 + (j * 512 + wv * 64) * 8);
            gl_lds16(srcU[j] + kk, base + 24576 + (j * 512 + wv * 64) * 8);
        }
    };

    bf16x8 a[4], bg[4], bu[4];
    auto load_frags = [&](int u, int co) {   // 12 ds_read_b128
        const unsigned short* base = lds + (u & 1) * 32768;
#pragma unroll
        for (int i = 0; i < 4; i++) a[i] = *(const bf16x8*)(base + arow[i] + co);
#pragma unroll
        for (int i = 0; i < 4; i++) bg[i] = *(const bf16x8*)(base + 16384 + brow[i] + co);
#pragma unroll
        for (int i = 0; i < 4; i++) bu[i] = *(const bf16x8*)(base + 24576 + brow[i] + co);
    };

    const int NT = D_MODEL / 64;   // 16
    stage(0);
    MEMFENCE;
    asm volatile("s_waitcnt vmcnt(0)" ::: "memory");
    __builtin_amdgcn_s_barrier();
    MEMFENCE;
    load_frags(0, co0);

    for (int t = 0; t < NT; ++t) {
        if (t + 1 < NT) stage(t + 1);          // VMEM issue first; lands under MFMA
        __builtin_amdgcn_sched_barrier(0);
        __builtin_amdgcn_s_setprio(1);
#pragma unroll
        for (int fm = 0; fm < 4; fm++)
#pragma unroll
            for (int fn = 0; fn < 4; fn++) {
                accg[fm][fn] = __builtin_amdgcn_mfma_f32_16x16x32_bf16(a[fm], bg[fn], accg[fm][fn], 0, 0, 0);
                accu[fm][fn] = __builtin_amdgcn_mfma_f32_16x16x32_bf16(a[fm], bu[fn], accu[fm][fn], 0, 0, 0);
            }
        __builtin_amdgcn_s_setprio(0);
        load_frags(t, co1);                    // ks1 frags; scheduler interleaves
        __builtin_amdgcn_s_setprio(1);
#pragma unroll
        for (int fm = 0; fm < 4; fm++)
#pragma unroll
            for (int fn = 0; fn < 4; fn++) {
                accg[fm][fn] = __builtin_amdgcn_mfma_f32_16x16x32_bf16(a[fm], bg[fn], accg[fm][fn], 0, 0, 0);
                accu[fm][fn] = __builtin_amdgcn_mfma_f32_16x16x32_bf16(a[fm], bu[fn], accu[fm][fn], 0, 0, 0);
            }
        __builtin_amdgcn_s_setprio(0);
        __builtin_amdgcn_sched_barrier(0);
        asm volatile("s_waitcnt vmcnt(0)" ::: "memory");   // my stage(t+1) landed
        __builtin_amdgcn_s_barrier();                       // all waves' landed; bufs safe
        MEMFENCE;
        if (t + 1 < NT) load_frags(t + 1, co0);             // next-step ks0 frags
    }

#pragma unroll
    for (int fm = 0; fm < 4; fm++)
#pragma unroll
        for (int fn = 0; fn < 4; fn++)
#pragma unroll
            for (int r = 0; r < 4; r++) {
                int m = wm * 64 + fm * 16 + kgrp * 4 + r;
                if (m < Mloc) {
                    int n = wn * 64 + fn * 16 + lrow;
                    float g = accg[fm][fn][r], u = accu[fm][fn][r];
                    float h = g / (1.f + __expf(-g)) * u;
                    H[(size_t)(row0 + m) * D_INNER + f0 + n] = f2b(h);
                }
            }
}

// ---------------- down GEMM + weighted scatter ----------------
// 512 threads / 8 waves (2M x 4N), tile M=128 x N=256, BK=64, 2 x 48KB LDS buffers.
__global__ __launch_bounds__(512, 2) void moe_down(
    const unsigned short* __restrict__ H, const unsigned short* __restrict__ wdT,
    const int* __restrict__ meta, const int* __restrict__ tok_of_slot,
    const float* __restrict__ w_of_slot, float* __restrict__ out, int S2)
{
    extern __shared__ __align__(16) unsigned short lds[];   // 2 * 24576 ushorts
    __shared__ int toks[128];
    __shared__ float wts[128];

    int lin = blockIdx.x;
    int d0 = (lin & 3) * 256;
    int tix = lin >> 2;
    int packed = meta[64 + tix];
    if (packed < 0) return;
    int e = packed >> 16, row0 = packed & 0xffff;
    int Mloc = min(128, meta[e + 1] - row0);

    int tid = threadIdx.x, wv = tid >> 6, lane = tid & 63;
    if (tid < 128) {
        bool v = tid < Mloc;
        toks[tid] = v ? tok_of_slot[row0 + tid] : 0;
        wts[tid] = v ? w_of_slot[row0 + tid] : 0.f;
    }
    int c = tid & 7, rr = tid >> 3;

    const unsigned short* srcA[2];
    const unsigned short* srcB[4];
#pragma unroll
    for (int j = 0; j < 2; j++) {
        int row = j * 64 + rr;
        int slot = min(row0 + row, S2 - 1);
        srcA[j] = H + (size_t)slot * D_INNER + 8 * (c ^ (row & 7));
    }
#pragma unroll
    for (int j = 0; j < 4; j++) {
        int row = j * 64 + rr;
        srcB[j] = wdT + (size_t)e * D_INNER * D_MODEL + (size_t)(d0 + row) * D_INNER + 8 * (c ^ (row & 7));
    }

    int wm = wv >> 2, wn = wv & 3;
    int lrow = lane & 15, kgrp = lane >> 4;
    int sw = lrow & 7;
    int co0 = 8 * (kgrp ^ sw);
    int co1 = 8 * ((4 + kgrp) ^ sw);

    int arow[4], brow[4];
#pragma unroll
    for (int i = 0; i < 4; i++) arow[i] = (wm * 64 + i * 16 + lrow) * 64;
#pragma unroll
    for (int i = 0; i < 4; i++) brow[i] = 8192 + (wn * 64 + i * 16 + lrow) * 64;

    f32x4 acc[4][4];
#pragma unroll
    for (int i = 0; i < 4; i++)
#pragma unroll
        for (int j = 0; j < 4; j++) acc[i][j] = (f32x4){0.f, 0.f, 0.f, 0.f};

    auto stage = [&](int u) {   // 6 gl_lds16 per thread: A 16KB + B 32KB
        int kk = u * 64;
        unsigned short* base = lds + (u & 1) * 24576;
#pragma unroll
        for (int j = 0; j < 2; j++)
            gl_lds16(srcA[j] + kk, base + (j * 512 + wv * 64) * 8);
#pragma unroll
        for (int j = 0; j < 4; j++)
            gl_lds16(srcB[j] + kk, base + 8192 + (j * 512 + wv * 64) * 8);
    };

    bf16x8 a[4], b[4];
    auto load_frags = [&](int u, int co) {   // 8 ds_read_b128
        const unsigned short* base = lds + (u & 1) * 24576;
#pragma unroll
        for (int i = 0; i < 4; i++) a[i] = *(const bf16x8*)(base + arow[i] + co);
#pragma unroll
        for (int i = 0; i < 4; i++) b[i] = *(const bf16x8*)(base + brow[i] + co);
    };

    const int NT = D_INNER / 64;   // 32
    stage(0);
    MEMFENCE;
    asm volatile("s_waitcnt vmcnt(0)" ::: "memory");
    __builtin_amdgcn_s_barrier();
    MEMFENCE;
    load_frags(0, co0);

    for (int t = 0; t < NT; ++t) {
        if (t + 1 < NT) stage(t + 1);
        __builtin_amdgcn_sched_barrier(0);
        __builtin_amdgcn_s_setprio(1);
#pragma unroll
        for (int fm = 0; fm < 4; fm++)
#pragma unroll
            for (int fn = 0; fn < 4; fn++)
                acc[fm][fn] = __builtin_amdgcn_mfma_f32_16x16x32_bf16(a[fm], b[fn], acc[fm][fn], 0, 0, 0);
        __builtin_amdgcn_s_setprio(0);
        load_frags(t, co1);
        __builtin_amdgcn_s_setprio(1);
#pragma unroll
        for (int fm = 0; fm < 4; fm++)
#pragma unroll
            for (int fn = 0; fn < 4; fn++)
                acc[fm][fn] = __builtin_amdgcn_mfma_f32_16x16x32_bf16(a[fm], b[fn], acc[fm][fn], 0, 0, 0);
        __builtin_amdgcn_s_setprio(0);
        __builtin_amdgcn_sched_barrier(0);
        asm volatile("s_waitcnt vmcnt(0)" ::: "memory");
        __builtin_amdgcn_s_barrier();
        MEMFENCE;
        if (t + 1 < NT) load_frags(t + 1, co0);
    }

#pragma unroll
    for (int fm = 0; fm < 4; fm++)
#pragma unroll
        for (int fn = 0; fn < 4; fn++)
#pragma unroll
            for (int r = 0; r < 4; r++) {
                int m = wm * 64 + fm * 16 + kgrp * 4 + r;
                if (m < Mloc) {
                    int n = wn * 64 + fn * 16 + lrow;
                    atomicAdd(&out[(size_t)toks[m] * D_MODEL + d0 + n], wts[m] * acc[fm][fn][r]);
                }
            }
}

extern "C" void kernel_launch(void* const* d_in, const int* in_sizes, int n_in,
                              void* d_out, int out_size, void* d_ws, size_t ws_size,
                              hipStream_t stream) {
    const float* x  = (const float*)d_in[0];
    const float* rw = (const float*)d_in[1];
    const float* rb = (const float*)d_in[2];
    const float* gw = (const float*)d_in[3];
    const float* uw = (const float*)d_in[4];
    const float* dw = (const float*)d_in[5];
    float* out = (float*)d_out;

    int T = in_sizes[0] / D_MODEL;   // 4096
    int S2 = 2 * T;                   // 8192 slots

    char* ws = (char*)d_ws;
    size_t cur = 0;
    auto take = [&](size_t bytes) { char* p = ws + cur; cur = (cur + bytes + 255) & ~(size_t)255; return p; };
    int*   top_i = (int*)take((size_t)S2 * 4);
    float* top_w = (float*)take((size_t)S2 * 4);
    int*   meta  = (int*)take(1024);
    int*   tos   = (int*)take((size_t)S2 * 4);
    float* wos   = (float*)take((size_t)S2 * 4);
    unsigned short* xb  = (unsigned short*)take((size_t)T * D_MODEL * 2);
    unsigned short* wgT = (unsigned short*)take((size_t)NEXP * D_MODEL * D_INNER * 2);
    unsigned short* wuT = (unsigned short*)take((size_t)NEXP * D_MODEL * D_INNER * 2);
    unsigned short* wdT = (unsigned short*)take((size_t)NEXP * D_MODEL * D_INNER * 2);
    unsigned short* H   = (unsigned short*)take((size_t)S2 * D_INNER * 2);

    static const int GU_LDS = 2 * 32768 * 2;   // 131072 B
    static const int DN_LDS = 2 * 24576 * 2;   // 98304 B
    hipFuncSetAttribute((const void*)moe_gate_up,
                        hipFuncAttributeMaxDynamicSharedMemorySize, GU_LDS);
    hipFuncSetAttribute((const void*)moe_down,
                        hipFuncAttributeMaxDynamicSharedMemorySize, DN_LDS);

    hipMemsetAsync(d_out, 0, (size_t)out_size * sizeof(float), stream);

    tcast3_kernel<<<dim3(32, 32, 24), 256, 0, stream>>>(gw, uw, dw, wgT, wuT, wdT);
    router_kernel<<<T, 64, 0, stream>>>(x, rw, rb, xb, top_i, top_w, T);
    bucket_kernel<<<1, 256, 0, stream>>>(top_i, top_w, meta, tos, wos, T);

    moe_gate_up<<<T256 * 16, 512, GU_LDS, stream>>>(xb, wgT, wuT, meta, tos, H);
    moe_down<<<T128 * 4, 512, DN_LDS, stream>>>(H, wdT, meta, tos, wos, out, S2);
}